// Round 5
// baseline (161.896 us; speedup 1.0000x reference)
//
#include <hip/hip_runtime.h>
#include <hip/hip_bf16.h>

// Shapes (fixed): B=2 T=1024 E=1024 H=8 W=31 D=63
// NTOK=2048, H*D=504 (pad 512), 3*H*D=1512 (pad 1536), 4E=4096

typedef __bf16 bf16;
typedef bf16 bf16x8 __attribute__((ext_vector_type(8)));
typedef bf16 bf16x4 __attribute__((ext_vector_type(4)));
typedef bf16 bf16x2 __attribute__((ext_vector_type(2)));
typedef float f32x4 __attribute__((ext_vector_type(4)));

// ---------------- fused rotary + layernorm1 --------------------------------
__global__ __launch_bounds__(256) void rotary_ln_kernel(
    const float* __restrict__ x, const float* __restrict__ w,
    const float* __restrict__ b, float* __restrict__ xr, bf16* __restrict__ Y)
{
    const int row = blockIdx.x;
    const int tid = threadIdx.x;
    float2 xv = *(const float2*)(x + (size_t)row * 512 + tid * 2);
    float i0 = exp2f(-(float)(2*tid)     * 0.025952563241307518f);
    float i1 = exp2f(-(float)(2*tid + 1) * 0.025952563241307518f);
    float a0 = xv.x * i0, a1 = xv.y * i1;
    float s0 = sinf(a0), s1 = sinf(a1);
    float c0 = cosf(a0), c1 = cosf(a1);
    *(float2*)(xr + (size_t)row * 1024 + tid*2)       = make_float2(s0, s1);
    *(float2*)(xr + (size_t)row * 1024 + 512 + tid*2) = make_float2(c0, c1);
    float s  = s0 + s1 + c0 + c1;
    float ss = s0*s0 + s1*s1 + c0*c0 + c1*c1;
    #pragma unroll
    for (int off = 32; off > 0; off >>= 1) {
        s  += __shfl_down(s, off);
        ss += __shfl_down(ss, off);
    }
    __shared__ float rs[4], rss[4];
    int wave = tid >> 6, lane = tid & 63;
    if (lane == 0) { rs[wave] = s; rss[wave] = ss; }
    __syncthreads();
    s  = rs[0] + rs[1] + rs[2] + rs[3];
    ss = rss[0] + rss[1] + rss[2] + rss[3];
    float mu   = s * (1.f / 1024.f);
    float var  = ss * (1.f / 1024.f) - mu * mu;
    float rstd = rsqrtf(var + 1e-5f);
    float2 w0 = *(const float2*)(w + tid*2);
    float2 b0 = *(const float2*)(b + tid*2);
    float2 w1 = *(const float2*)(w + 512 + tid*2);
    float2 b1 = *(const float2*)(b + 512 + tid*2);
    bf16x2 y0, y1;
    y0[0] = (bf16)((s0 - mu) * rstd * w0.x + b0.x);
    y0[1] = (bf16)((s1 - mu) * rstd * w0.y + b0.y);
    y1[0] = (bf16)((c0 - mu) * rstd * w1.x + b1.x);
    y1[1] = (bf16)((c1 - mu) * rstd * w1.y + b1.y);
    *(bf16x2*)(Y + (size_t)row * 1024 + tid*2)       = y0;
    *(bf16x2*)(Y + (size_t)row * 1024 + 512 + tid*2) = y1;
}

// ---------------- layernorm (fp32 in, bf16 out), one block per row --------
__global__ __launch_bounds__(256) void ln_bf16_kernel(
    const float* __restrict__ X, const float* __restrict__ w,
    const float* __restrict__ b, bf16* __restrict__ Y)
{
    int row = blockIdx.x;
    const float4* xp = (const float4*)(X + (size_t)row * 1024);
    float4 xv = xp[threadIdx.x];
    float s  = xv.x + xv.y + xv.z + xv.w;
    float ss = xv.x*xv.x + xv.y*xv.y + xv.z*xv.z + xv.w*xv.w;
    #pragma unroll
    for (int off = 32; off > 0; off >>= 1) {
        s  += __shfl_down(s, off);
        ss += __shfl_down(ss, off);
    }
    __shared__ float rs[4], rss[4];
    int wave = threadIdx.x >> 6, lane = threadIdx.x & 63;
    if (lane == 0) { rs[wave] = s; rss[wave] = ss; }
    __syncthreads();
    s  = rs[0] + rs[1] + rs[2] + rs[3];
    ss = rss[0] + rss[1] + rss[2] + rss[3];
    float mu  = s * (1.f / 1024.f);
    float var = ss * (1.f / 1024.f) - mu * mu;
    float rstd = rsqrtf(var + 1e-5f);
    float4 wv = ((const float4*)w)[threadIdx.x];
    float4 bv = ((const float4*)b)[threadIdx.x];
    bf16 y[4];
    y[0] = (bf16)((xv.x - mu) * rstd * wv.x + bv.x);
    y[1] = (bf16)((xv.y - mu) * rstd * wv.y + bv.y);
    y[2] = (bf16)((xv.z - mu) * rstd * wv.z + bv.z);
    y[3] = (bf16)((xv.w - mu) * rstd * wv.w + bv.w);
    *(uint2*)(Y + (size_t)row * 1024 + threadIdx.x * 4) = *(uint2*)y;
}

// ---------------- fused weight converts (fp32->bf16, zero-pad) + bias pad --
__device__ __forceinline__ void conv_chunk(
    const float* __restrict__ src, bf16* __restrict__ dst,
    int ci, int N, int K, int Kp)
{
    int kpc = Kp >> 3;
    int r  = ci / kpc;
    int kc = (ci - r * kpc) << 3;
    bf16x8 o;
    if (r < N && kc < K) {
        float4 f0 = *(const float4*)(src + (size_t)r * K + kc);
        float4 f1 = *(const float4*)(src + (size_t)r * K + kc + 4);
        o[0]=(bf16)f0.x; o[1]=(bf16)f0.y; o[2]=(bf16)f0.z; o[3]=(bf16)f0.w;
        o[4]=(bf16)f1.x; o[5]=(bf16)f1.y; o[6]=(bf16)f1.z; o[7]=(bf16)f1.w;
    } else {
        #pragma unroll
        for (int j = 0; j < 8; ++j) o[j] = (bf16)0.f;
    }
    *(bf16x8*)(dst + (size_t)r * Kp + kc) = o;
}

__global__ __launch_bounds__(256) void conv_all_kernel(
    const float* __restrict__ qkv_w, const float* __restrict__ proj_w,
    const float* __restrict__ fc_w,  const float* __restrict__ cproj_w,
    const float* __restrict__ qkv_b,
    bf16* __restrict__ wqkv, bf16* __restrict__ wproj,
    bf16* __restrict__ wfc,  bf16* __restrict__ wcproj,
    float* __restrict__ qkvb_p)
{
    if (blockIdx.x == 5120) {
        for (int i = threadIdx.x; i < 1536; i += 256)
            qkvb_p[i] = (i < 1512) ? qkv_b[i] : 0.f;
        return;
    }
    int idx = blockIdx.x * 256 + threadIdx.x;
    if      (idx < 196608)  conv_chunk(qkv_w,   wqkv,   idx,          1512, 1024, 1024);
    else if (idx < 262144)  conv_chunk(proj_w,  wproj,  idx - 196608, 1024,  504,  512);
    else if (idx < 786432)  conv_chunk(fc_w,    wfc,    idx - 262144, 4096, 1024, 1024);
    else                    conv_chunk(cproj_w, wcproj, idx - 786432, 1024, 4096, 4096);
}

// ---------------- waitcnt helpers ------------------------------------------
template<int N> __device__ __forceinline__ void vmwait()
{
    if constexpr      (N==0) asm volatile("s_waitcnt vmcnt(0)" ::: "memory");
    else if constexpr (N==4) asm volatile("s_waitcnt vmcnt(4)" ::: "memory");
    else if constexpr (N==8) asm volatile("s_waitcnt vmcnt(8)" ::: "memory");
}
__device__ __forceinline__ void lgkmwait0()
{
    asm volatile("s_waitcnt lgkmcnt(0)" ::: "memory");
}
__device__ __forceinline__ void hw_barrier()
{
    asm volatile("s_barrier" ::: "memory");
}

// ---------------- bf16 MFMA GEMM: 128x128, 4-buffer 2-ahead, T2 swizzle ----
// C = A[M,Kp] @ W[Np,Kp]^T (+ bias).  BM=BN=128, BK=32, 4 waves (2x2).
// LDS: 4 buffers x (A[128][32] + B[128][32]) = 64 KB -> 2 blocks/CU.
// T2: byte ^= (row&3)<<4 applied to pre-swizzled GLOBAL source (LDS dest
// linear, rule 21) and to the ds_read address -> 8-way -> 4-way conflicts.
// Pipeline: stage tile kt+3 at top of body kt (2 tiles in flight), counted
// vmcnt(8/4/0); lgkmcnt(0)+raw s_barrier per tile (reads complete pre-barrier
// -> stage of kt+4 next body can't corrupt buf kt&3).
// EPI: 0 bf16 out, 1 gelu->bf16, 2 +R->fp32, 3 partial->bf16 (no bias)
__device__ __forceinline__ float gelu_exact(float v)
{
    return 0.5f * v * (1.f + erff(v * 0.70710678118654752f));
}

template<int EPI>
__global__ __launch_bounds__(256, 2) void gemm5_kernel(
    const bf16* __restrict__ A, const bf16* __restrict__ Wt,
    const float* __restrict__ bias, const float* R,
    float* Cf, bf16* Cb, int N, int Kp, int ksplit)
{
    __shared__ __align__(16) char lds[4][16384];   // per buf: A 8KB | B 8KB

    const int tid  = threadIdx.x;
    const int w    = tid >> 6;
    const int lane = tid & 63;
    const int row0 = blockIdx.y * 128;
    const int col0 = blockIdx.x * 128;
    const int wr = (w >> 1) * 64;
    const int wc = (w & 1) * 64;
    const int rl = lane & 15;
    // swizzled k-byte offset within a 64B LDS row (same for A and B reads)
    const int koff = (((lane >> 4) << 4) ^ ((rl & 3) << 4));

    const size_t strideBy = (size_t)Kp * 2;
    const size_t kz = (size_t)blockIdx.z * ksplit * 2;   // split byte offset
    const char* Abase = (const char*)A  + (size_t)row0 * strideBy + kz;
    const char* Wbase = (const char*)Wt + (size_t)col0 * strideBy + kz;

    // kt-invariant pre-swizzled source offsets (dest LDS byte o is linear)
    size_t srcA[2], srcB[2];
    #pragma unroll
    for (int i = 0; i < 2; ++i) {
        int o = (i * 256 + tid) * 16;
        int r = o >> 6;
        int c = (o & 63) ^ ((r & 3) << 4);
        srcA[i] = (size_t)r * strideBy + c;
        srcB[i] = srcA[i];
    }

    f32x4 acc[4][4] = {};

    auto STAGE = [&](int buf, int kt) {
        const char* ab = Abase + (size_t)kt * 64;
        const char* wb = Wbase + (size_t)kt * 64;
        #pragma unroll
        for (int i = 0; i < 2; ++i)
            __builtin_amdgcn_global_load_lds(
                (const __attribute__((address_space(1))) void*)(ab + srcA[i]),
                (__attribute__((address_space(3))) void*)(&lds[buf][0] + (i*256 + tid)*16),
                16, 0, 0);
        #pragma unroll
        for (int i = 0; i < 2; ++i)
            __builtin_amdgcn_global_load_lds(
                (const __attribute__((address_space(1))) void*)(wb + srcB[i]),
                (__attribute__((address_space(3))) void*)(&lds[buf][8192] + (i*256 + tid)*16),
                16, 0, 0);
    };

    const int niter = ksplit >> 5;      // BK = 32; all call sites niter >= 3
    STAGE(0, 0);
    STAGE(1, 1);
    STAGE(2, 2);
    vmwait<8>();                        // tile 0 landed; 1,2 in flight
    hw_barrier();

    for (int kt = 0; kt < niter; ++kt) {
        if (kt + 3 < niter)
            STAGE((kt + 3) & 3, kt + 3);   // overwrites buf (kt-1)&3: all waves
                                           // past barrier kt -> reads done
        const char* base = lds[kt & 3];
        bf16x8 af[4], bfr[4];
        #pragma unroll
        for (int mi = 0; mi < 4; ++mi)
            af[mi] = *(const bf16x8*)(base + (size_t)((wr + mi*16 + rl) << 6) + koff);
        #pragma unroll
        for (int nj = 0; nj < 4; ++nj)
            bfr[nj] = *(const bf16x8*)(base + 8192 + (size_t)((wc + nj*16 + rl) << 6) + koff);
        __builtin_amdgcn_s_setprio(1);
        #pragma unroll
        for (int mi = 0; mi < 4; ++mi)
            #pragma unroll
            for (int nj = 0; nj < 4; ++nj)
                acc[mi][nj] = __builtin_amdgcn_mfma_f32_16x16x32_bf16(
                    af[mi], bfr[nj], acc[mi][nj], 0, 0, 0);
        __builtin_amdgcn_s_setprio(0);

        if (kt + 1 < niter) {
            lgkmwait0();                   // my ds_reads complete pre-barrier
            if (kt + 3 < niter)      vmwait<8>();  // kt+1 landed; 2 in flight
            else if (kt + 2 < niter) vmwait<4>();  // kt+1 landed; 1 in flight
            else                     vmwait<0>();  // last tile landed
            hw_barrier();
        }
    }

    // C/D layout: col = lane&15, row = (lane>>4)*4 + reg   [m89/m91]
    const int rq = (lane >> 4) * 4;
    bf16* Cbz = Cb;
    if (EPI == 3) Cbz += (size_t)blockIdx.z * 2048 * N;
    #pragma unroll
    for (int mi = 0; mi < 4; ++mi) {
        #pragma unroll
        for (int rj = 0; rj < 4; ++rj) {
            int row = row0 + wr + mi*16 + rq + rj;
            #pragma unroll
            for (int nj = 0; nj < 4; ++nj) {
                int col = col0 + wc + nj*16 + rl;
                float c = acc[mi][nj][rj];
                if (EPI != 3) c += bias[col];
                size_t off = (size_t)row * N + col;
                if (EPI == 0)      Cb[off]  = (bf16)c;
                else if (EPI == 1) Cb[off]  = (bf16)gelu_exact(c);
                else if (EPI == 3) Cbz[off] = (bf16)c;
                else               Cf[off]  = c + R[off];
            }
        }
    }
}

// ---------------- cproj split-K reducer: out += bias + p0 + p1 -------------
__global__ __launch_bounds__(256) void cproj_reduce_kernel(
    const bf16* __restrict__ parts, const float* __restrict__ bias,
    float* out)
{
    int row = blockIdx.x;
    int c = threadIdx.x * 4;
    size_t off = (size_t)row * 1024 + c;
    bf16x4 a = *(const bf16x4*)(parts + off);
    bf16x4 b = *(const bf16x4*)(parts + (size_t)2048*1024 + off);
    float4 bv = *(const float4*)(bias + c);
    float4 o = *(float4*)(out + off);
    o.x += bv.x + (float)a[0] + (float)b[0];
    o.y += bv.y + (float)a[1] + (float)b[1];
    o.z += bv.z + (float)a[2] + (float)b[2];
    o.w += bv.w + (float)a[3] + (float)b[3];
    *(float4*)(out + off) = o;
}

// ---------------- windowed attention, one wave per (b,h,t) token ----------
__global__ __launch_bounds__(256) void attn_kernel(
    const bf16* __restrict__ qkv, const float* __restrict__ rel_pos,
    bf16* __restrict__ outp)
{
    __shared__ float sbias[64*65];      // bias[d][v] at d*65+v
    __shared__ float kmw[4][3][64];
    for (int i = threadIdx.x; i < 63*63; i += 256) {
        int d = i / 63, v = i - d*63;
        sbias[d*65 + v] = rel_pos[((d + 32) % 63) * 63 + v];
    }
    __syncthreads();
    const int wave = threadIdx.x >> 6;
    const int lane = threadIdx.x & 63;
    const int tk  = blockIdx.x * 4 + wave;
    const int row = tk >> 3;
    const int h   = tk & 7;
    const bf16* base = qkv + (size_t)row * 1536 + h * 63;
    float q_own = 0.f, k_own = 0.f, v_own = 0.f;
    if (lane < 63) {
        q_own = (float)base[lane];
        k_own = (float)base[504 + lane];
        v_own = (float)base[1008 + lane];
    }
    float m = -1e30f;
    for (int d = 0; d < 63; ++d) {
        float qd = __shfl(q_own, d);
        m = fmaxf(m, fmaf(qd, k_own, sbias[d*65 + lane]));
    }
    float Z = 0.f;
    for (int d = 0; d < 63; ++d) {
        float qd = __shfl(q_own, d);
        Z += __expf(fmaf(qd, k_own, sbias[d*65 + lane]) - m);
    }
    kmw[wave][0][lane] = k_own;
    kmw[wave][1][lane] = m;
    kmw[wave][2][lane] = v_own / Z;
    float acc = 0.f;
    for (int v = 0; v < 63; ++v) {
        float s = fmaf(q_own, kmw[wave][0][v], sbias[lane*65 + v]) - kmw[wave][1][v];
        acc += __expf(s) * kmw[wave][2][v];
    }
    if (lane < 63)
        outp[(size_t)row * 512 + h*63 + lane] = (bf16)acc;
    if (h == 7 && lane == 63) {
        #pragma unroll
        for (int j = 0; j < 8; ++j)
            outp[(size_t)row * 512 + 504 + j] = (bf16)0.f;
    }
}

extern "C" void kernel_launch(void* const* d_in, const int* in_sizes, int n_in,
                              void* d_out, int out_size, void* d_ws, size_t ws_size,
                              hipStream_t stream)
{
    const float* x       = (const float*)d_in[0];
    const float* ln1_w   = (const float*)d_in[1];
    const float* ln1_b   = (const float*)d_in[2];
    const float* qkv_w   = (const float*)d_in[3];
    const float* qkv_b   = (const float*)d_in[4];
    const float* rel_pos = (const float*)d_in[5];
    const float* proj_w  = (const float*)d_in[6];
    const float* proj_b  = (const float*)d_in[7];
    const float* ln2_w   = (const float*)d_in[8];
    const float* ln2_b   = (const float*)d_in[9];
    const float* fc_w    = (const float*)d_in[10];
    const float* fc_b    = (const float*)d_in[11];
    const float* cproj_w = (const float*)d_in[12];
    const float* cproj_b = (const float*)d_in[13];
    float* out = (float*)d_out;

    // ---- workspace layout (bytes), total ~50 MB ----
    char* p = (char*)d_ws;
    float* xr      = (float*)p;            p += (size_t)2048*1024*4;   // 8 MB  [0..8M)
    bf16*  h_bf    = (bf16*)p;             p += (size_t)2048*1024*2;   // 4 MB  [8..12M)
    bf16*  wqkv    = (bf16*)p;             p += (size_t)1536*1024*2;   // 3 MB
    bf16*  wproj   = (bf16*)p;             p += (size_t)1024*512*2;    // 1 MB
    bf16*  wfc     = (bf16*)p;             p += (size_t)4096*1024*2;   // 8 MB
    bf16*  wcproj  = (bf16*)p;             p += (size_t)1024*4096*2;   // 8 MB
    float* qkvb_p  = (float*)p;            p += 8192;                  // 6 KB pad
    bf16*  attn_bf = (bf16*)p;             p += (size_t)2048*512*2;    // 2 MB
    bf16*  qkvb    = (bf16*)p;                                         // 6 MB
    bf16*  fc_act  = (bf16*)p;             // overlaps qkvb (dead after attn), 16 MB
    // cproj bf16 partials (2 x 4 MB) overlay xr+h_bf: both dead by cproj time
    bf16*  partials = (bf16*)d_ws;

    conv_all_kernel<<<5121, 256, 0, stream>>>(qkv_w, proj_w, fc_w, cproj_w, qkv_b,
                                              wqkv, wproj, wfc, wcproj, qkvb_p);
    rotary_ln_kernel<<<2048, 256, 0, stream>>>(x, ln1_w, ln1_b, xr, h_bf);
    gemm5_kernel<0><<<dim3(12,16,1), 256, 0, stream>>>(h_bf, wqkv, qkvb_p, nullptr,
                                                       nullptr, qkvb, 1536, 1024, 1024);
    attn_kernel<<<4096, 256, 0, stream>>>(qkvb, rel_pos, attn_bf);
    gemm5_kernel<2><<<dim3(8,16,1), 256, 0, stream>>>(attn_bf, wproj, proj_b, xr,
                                                      out, nullptr, 1024, 512, 512);
    ln_bf16_kernel<<<2048, 256, 0, stream>>>(out, ln2_w, ln2_b, h_bf);
    gemm5_kernel<1><<<dim3(32,16,1), 256, 0, stream>>>(h_bf, wfc, fc_b, nullptr,
                                                       nullptr, fc_act, 4096, 1024, 1024);
    gemm5_kernel<3><<<dim3(8,16,2), 256, 0, stream>>>(fc_act, wcproj, nullptr, nullptr,
                                                      nullptr, partials, 1024, 4096, 2048);
    cproj_reduce_kernel<<<2048, 256, 0, stream>>>(partials, cproj_b, out);
}

// Round 6
// 152.911 us; speedup vs baseline: 1.0588x; 1.0588x over previous
//
#include <hip/hip_runtime.h>
#include <hip/hip_bf16.h>

// Shapes (fixed): B=2 T=1024 E=1024 H=8 W=31 D=63
// NTOK=2048, H*D=504 (pad 512), 3*H*D=1512 (pad 1536), 4E=4096

typedef __bf16 bf16;
typedef bf16 bf16x8 __attribute__((ext_vector_type(8)));
typedef bf16 bf16x4 __attribute__((ext_vector_type(4)));
typedef bf16 bf16x2 __attribute__((ext_vector_type(2)));
typedef float f32x4 __attribute__((ext_vector_type(4)));

// ---------------- fused rotary + layernorm1 --------------------------------
__global__ __launch_bounds__(256) void rotary_ln_kernel(
    const float* __restrict__ x, const float* __restrict__ w,
    const float* __restrict__ b, float* __restrict__ xr, bf16* __restrict__ Y)
{
    const int row = blockIdx.x;
    const int tid = threadIdx.x;
    float2 xv = *(const float2*)(x + (size_t)row * 512 + tid * 2);
    float i0 = exp2f(-(float)(2*tid)     * 0.025952563241307518f);
    float i1 = exp2f(-(float)(2*tid + 1) * 0.025952563241307518f);
    float a0 = xv.x * i0, a1 = xv.y * i1;
    float s0 = sinf(a0), s1 = sinf(a1);
    float c0 = cosf(a0), c1 = cosf(a1);
    *(float2*)(xr + (size_t)row * 1024 + tid*2)       = make_float2(s0, s1);
    *(float2*)(xr + (size_t)row * 1024 + 512 + tid*2) = make_float2(c0, c1);
    float s  = s0 + s1 + c0 + c1;
    float ss = s0*s0 + s1*s1 + c0*c0 + c1*c1;
    #pragma unroll
    for (int off = 32; off > 0; off >>= 1) {
        s  += __shfl_down(s, off);
        ss += __shfl_down(ss, off);
    }
    __shared__ float rs[4], rss[4];
    int wave = tid >> 6, lane = tid & 63;
    if (lane == 0) { rs[wave] = s; rss[wave] = ss; }
    __syncthreads();
    s  = rs[0] + rs[1] + rs[2] + rs[3];
    ss = rss[0] + rss[1] + rss[2] + rss[3];
    float mu   = s * (1.f / 1024.f);
    float var  = ss * (1.f / 1024.f) - mu * mu;
    float rstd = rsqrtf(var + 1e-5f);
    float2 w0 = *(const float2*)(w + tid*2);
    float2 b0 = *(const float2*)(b + tid*2);
    float2 w1 = *(const float2*)(w + 512 + tid*2);
    float2 b1 = *(const float2*)(b + 512 + tid*2);
    bf16x2 y0, y1;
    y0[0] = (bf16)((s0 - mu) * rstd * w0.x + b0.x);
    y0[1] = (bf16)((s1 - mu) * rstd * w0.y + b0.y);
    y1[0] = (bf16)((c0 - mu) * rstd * w1.x + b1.x);
    y1[1] = (bf16)((c1 - mu) * rstd * w1.y + b1.y);
    *(bf16x2*)(Y + (size_t)row * 1024 + tid*2)       = y0;
    *(bf16x2*)(Y + (size_t)row * 1024 + 512 + tid*2) = y1;
}

// ---------------- layernorm (fp32 in, bf16 out), one block per row --------
__global__ __launch_bounds__(256) void ln_bf16_kernel(
    const float* __restrict__ X, const float* __restrict__ w,
    const float* __restrict__ b, bf16* __restrict__ Y)
{
    int row = blockIdx.x;
    const float4* xp = (const float4*)(X + (size_t)row * 1024);
    float4 xv = xp[threadIdx.x];
    float s  = xv.x + xv.y + xv.z + xv.w;
    float ss = xv.x*xv.x + xv.y*xv.y + xv.z*xv.z + xv.w*xv.w;
    #pragma unroll
    for (int off = 32; off > 0; off >>= 1) {
        s  += __shfl_down(s, off);
        ss += __shfl_down(ss, off);
    }
    __shared__ float rs[4], rss[4];
    int wave = threadIdx.x >> 6, lane = threadIdx.x & 63;
    if (lane == 0) { rs[wave] = s; rss[wave] = ss; }
    __syncthreads();
    s  = rs[0] + rs[1] + rs[2] + rs[3];
    ss = rss[0] + rss[1] + rss[2] + rss[3];
    float mu  = s * (1.f / 1024.f);
    float var = ss * (1.f / 1024.f) - mu * mu;
    float rstd = rsqrtf(var + 1e-5f);
    float4 wv = ((const float4*)w)[threadIdx.x];
    float4 bv = ((const float4*)b)[threadIdx.x];
    bf16 y[4];
    y[0] = (bf16)((xv.x - mu) * rstd * wv.x + bv.x);
    y[1] = (bf16)((xv.y - mu) * rstd * wv.y + bv.y);
    y[2] = (bf16)((xv.z - mu) * rstd * wv.z + bv.z);
    y[3] = (bf16)((xv.w - mu) * rstd * wv.w + bv.w);
    *(uint2*)(Y + (size_t)row * 1024 + threadIdx.x * 4) = *(uint2*)y;
}

// ---------------- fused weight converts (fp32->bf16, zero-pad) + bias pad --
__device__ __forceinline__ void conv_chunk(
    const float* __restrict__ src, bf16* __restrict__ dst,
    int ci, int N, int K, int Kp)
{
    int kpc = Kp >> 3;
    int r  = ci / kpc;
    int kc = (ci - r * kpc) << 3;
    bf16x8 o;
    if (r < N && kc < K) {
        float4 f0 = *(const float4*)(src + (size_t)r * K + kc);
        float4 f1 = *(const float4*)(src + (size_t)r * K + kc + 4);
        o[0]=(bf16)f0.x; o[1]=(bf16)f0.y; o[2]=(bf16)f0.z; o[3]=(bf16)f0.w;
        o[4]=(bf16)f1.x; o[5]=(bf16)f1.y; o[6]=(bf16)f1.z; o[7]=(bf16)f1.w;
    } else {
        #pragma unroll
        for (int j = 0; j < 8; ++j) o[j] = (bf16)0.f;
    }
    *(bf16x8*)(dst + (size_t)r * Kp + kc) = o;
}

__global__ __launch_bounds__(256) void conv_all_kernel(
    const float* __restrict__ qkv_w, const float* __restrict__ proj_w,
    const float* __restrict__ fc_w,  const float* __restrict__ cproj_w,
    const float* __restrict__ qkv_b,
    bf16* __restrict__ wqkv, bf16* __restrict__ wproj,
    bf16* __restrict__ wfc,  bf16* __restrict__ wcproj,
    float* __restrict__ qkvb_p)
{
    if (blockIdx.x == 5120) {
        for (int i = threadIdx.x; i < 1536; i += 256)
            qkvb_p[i] = (i < 1512) ? qkv_b[i] : 0.f;
        return;
    }
    int idx = blockIdx.x * 256 + threadIdx.x;
    if      (idx < 196608)  conv_chunk(qkv_w,   wqkv,   idx,          1512, 1024, 1024);
    else if (idx < 262144)  conv_chunk(proj_w,  wproj,  idx - 196608, 1024,  504,  512);
    else if (idx < 786432)  conv_chunk(fc_w,    wfc,    idx - 262144, 4096, 1024, 1024);
    else                    conv_chunk(cproj_w, wcproj, idx - 786432, 1024, 4096, 4096);
}

// ---------------- bf16 MFMA GEMM: 64x128 tile, 4 waves, 2-buffer ping-pong -
// C = A[M,Kp] @ W[Np,Kp]^T (+ bias).  BM=64, BN=128, BK=32.
// LDS: 2 x (A 4KB + B 8KB) = 24 KB -> up to 6 blocks/CU; grids sized so
// 2-4 blocks/CU are co-resident (m114 cross-block latency hiding; m102:
// blocks/CU is the controlling variable at this scale).
// Bijective XCD-chunked swizzle (nwg % 8 == 0 at all call sites).
// EPI: 0 bf16 out (+bias), 1 gelu->bf16 (+bias), 3 bf16 partial (no bias,
//      strided by blockIdx.z for split-K)
__device__ __forceinline__ float gelu_exact(float v)
{
    return 0.5f * v * (1.f + erff(v * 0.70710678118654752f));
}

template<int EPI>
__global__ __launch_bounds__(256, 4) void gemm6_kernel(
    const bf16* __restrict__ A, const bf16* __restrict__ Wt,
    const float* __restrict__ bias,
    float* Cf, bf16* Cb, int N, int Kp, int ksplit)
{
    __shared__ __align__(16) char lds[2][12288];   // per buf: A 4KB | B 8KB

    const int tid  = threadIdx.x;
    const int w    = tid >> 6;
    const int lane = tid & 63;

    // XCD-chunked bijective swizzle over linear block id
    const int gx = gridDim.x, gy = gridDim.y;
    const int nwg = gx * gy * gridDim.z;
    const int chunk = nwg >> 3;
    int id = (blockIdx.z * gy + blockIdx.y) * gx + blockIdx.x;
    int sw = (id & 7) * chunk + (id >> 3);
    const int bx = sw % gx;
    const int t2 = sw / gx;
    const int by = t2 % gy;
    const int bz = t2 / gy;

    const int row0 = by * 64;
    const int col0 = bx * 128;
    const int wr = (w >> 1) * 32;      // wave row offset (2 waves x 32 rows)
    const int wc = (w & 1) * 64;       // wave col offset (2 waves x 64 cols)
    const int rl = lane & 15;
    const int kb16 = (lane >> 4) * 16; // byte offset of 8-bf16 k-fragment

    const size_t strideBy = (size_t)Kp * 2;
    const size_t kz = (size_t)bz * ksplit * 2;
    const char* Abase = (const char*)A  + (size_t)row0 * strideBy + kz;
    const char* Wbase = (const char*)Wt + (size_t)col0 * strideBy + kz;

    // kt-invariant source offsets (LDS row = 64 B = 32 bf16)
    const size_t srcA0 = (size_t)(tid >> 2) * strideBy + (tid & 3) * 16;
    size_t srcB[2];
    #pragma unroll
    for (int i = 0; i < 2; ++i) {
        int o = (i * 256 + tid) * 16;
        srcB[i] = (size_t)(o >> 6) * strideBy + (o & 63);
    }

    f32x4 acc[2][4] = {};

    auto STAGE = [&](int buf, int kt) {
        const char* ab = Abase + (size_t)kt * 64;
        const char* wb = Wbase + (size_t)kt * 64;
        __builtin_amdgcn_global_load_lds(
            (const __attribute__((address_space(1))) void*)(ab + srcA0),
            (__attribute__((address_space(3))) void*)(&lds[buf][0] + tid * 16),
            16, 0, 0);
        #pragma unroll
        for (int i = 0; i < 2; ++i)
            __builtin_amdgcn_global_load_lds(
                (const __attribute__((address_space(1))) void*)(wb + srcB[i]),
                (__attribute__((address_space(3))) void*)(&lds[buf][4096] + (i*256 + tid)*16),
                16, 0, 0);
    };

    const int niter = ksplit >> 5;      // BK = 32
    STAGE(0, 0);
    __syncthreads();
    for (int kt = 0; kt < niter; ++kt) {
        if (kt + 1 < niter)
            STAGE((kt + 1) & 1, kt + 1);   // in flight during compute
        const char* base = lds[kt & 1];
        bf16x8 af[2], bfr[4];
        #pragma unroll
        for (int mi = 0; mi < 2; ++mi)
            af[mi] = *(const bf16x8*)(base + ((wr + mi*16 + rl) << 6) + kb16);
        #pragma unroll
        for (int nj = 0; nj < 4; ++nj)
            bfr[nj] = *(const bf16x8*)(base + 4096 + ((wc + nj*16 + rl) << 6) + kb16);
        __builtin_amdgcn_s_setprio(1);
        #pragma unroll
        for (int mi = 0; mi < 2; ++mi)
            #pragma unroll
            for (int nj = 0; nj < 4; ++nj)
                acc[mi][nj] = __builtin_amdgcn_mfma_f32_16x16x32_bf16(
                    af[mi], bfr[nj], acc[mi][nj], 0, 0, 0);
        __builtin_amdgcn_s_setprio(0);
        __syncthreads();                   // drain loads + protect ping-pong
    }

    // C/D layout: col = lane&15, row = (lane>>4)*4 + reg   [m89/m91]
    const int rq = (lane >> 4) * 4;
    bf16* Cbz = Cb;
    if (EPI == 3) Cbz += (size_t)bz * 2048 * N;
    #pragma unroll
    for (int mi = 0; mi < 2; ++mi) {
        #pragma unroll
        for (int rj = 0; rj < 4; ++rj) {
            int row = row0 + wr + mi*16 + rq + rj;
            #pragma unroll
            for (int nj = 0; nj < 4; ++nj) {
                int col = col0 + wc + nj*16 + rl;
                float c = acc[mi][nj][rj];
                if (EPI != 3) c += bias[col];
                size_t off = (size_t)row * N + col;
                if (EPI == 0)      Cb[off]  = (bf16)c;
                else if (EPI == 1) Cb[off]  = (bf16)gelu_exact(c);
                else               Cbz[off] = (bf16)c;
            }
        }
    }
}

// ---------------- split-K reducer: out = R + bias + sum(parts) -------------
// N = 1024 fixed; P partials of [2048][1024] bf16. R may alias out.
template<int P>
__global__ __launch_bounds__(256) void reduce_kernel(
    const bf16* __restrict__ parts, const float* __restrict__ bias,
    const float* R, float* out)
{
    int row = blockIdx.x;
    int c = threadIdx.x * 4;
    size_t off = (size_t)row * 1024 + c;
    float4 bv = *(const float4*)(bias + c);
    float4 o = *(const float4*)(R + off);
    o.x += bv.x; o.y += bv.y; o.z += bv.z; o.w += bv.w;
    #pragma unroll
    for (int p = 0; p < P; ++p) {
        bf16x4 v = *(const bf16x4*)(parts + (size_t)p * 2048 * 1024 + off);
        o.x += (float)v[0]; o.y += (float)v[1];
        o.z += (float)v[2]; o.w += (float)v[3];
    }
    *(float4*)(out + off) = o;
}

// ---------------- windowed attention, one wave per (b,h,t) token ----------
__global__ __launch_bounds__(256) void attn_kernel(
    const bf16* __restrict__ qkv, const float* __restrict__ rel_pos,
    bf16* __restrict__ outp)
{
    __shared__ float sbias[64*65];      // bias[d][v] at d*65+v
    __shared__ float kmw[4][3][64];
    for (int i = threadIdx.x; i < 63*63; i += 256) {
        int d = i / 63, v = i - d*63;
        sbias[d*65 + v] = rel_pos[((d + 32) % 63) * 63 + v];
    }
    __syncthreads();
    const int wave = threadIdx.x >> 6;
    const int lane = threadIdx.x & 63;
    const int tk  = blockIdx.x * 4 + wave;
    const int row = tk >> 3;
    const int h   = tk & 7;
    const bf16* base = qkv + (size_t)row * 1536 + h * 63;
    float q_own = 0.f, k_own = 0.f, v_own = 0.f;
    if (lane < 63) {
        q_own = (float)base[lane];
        k_own = (float)base[504 + lane];
        v_own = (float)base[1008 + lane];
    }
    float m = -1e30f;
    for (int d = 0; d < 63; ++d) {
        float qd = __shfl(q_own, d);
        m = fmaxf(m, fmaf(qd, k_own, sbias[d*65 + lane]));
    }
    float Z = 0.f;
    for (int d = 0; d < 63; ++d) {
        float qd = __shfl(q_own, d);
        Z += __expf(fmaf(qd, k_own, sbias[d*65 + lane]) - m);
    }
    kmw[wave][0][lane] = k_own;
    kmw[wave][1][lane] = m;
    kmw[wave][2][lane] = v_own / Z;
    float acc = 0.f;
    for (int v = 0; v < 63; ++v) {
        float s = fmaf(q_own, kmw[wave][0][v], sbias[lane*65 + v]) - kmw[wave][1][v];
        acc += __expf(s) * kmw[wave][2][v];
    }
    if (lane < 63)
        outp[(size_t)row * 512 + h*63 + lane] = (bf16)acc;
    if (h == 7 && lane == 63) {
        #pragma unroll
        for (int j = 0; j < 8; ++j)
            outp[(size_t)row * 512 + 504 + j] = (bf16)0.f;
    }
}

extern "C" void kernel_launch(void* const* d_in, const int* in_sizes, int n_in,
                              void* d_out, int out_size, void* d_ws, size_t ws_size,
                              hipStream_t stream)
{
    const float* x       = (const float*)d_in[0];
    const float* ln1_w   = (const float*)d_in[1];
    const float* ln1_b   = (const float*)d_in[2];
    const float* qkv_w   = (const float*)d_in[3];
    const float* qkv_b   = (const float*)d_in[4];
    const float* rel_pos = (const float*)d_in[5];
    const float* proj_w  = (const float*)d_in[6];
    const float* proj_b  = (const float*)d_in[7];
    const float* ln2_w   = (const float*)d_in[8];
    const float* ln2_b   = (const float*)d_in[9];
    const float* fc_w    = (const float*)d_in[10];
    const float* fc_b    = (const float*)d_in[11];
    const float* cproj_w = (const float*)d_in[12];
    const float* cproj_b = (const float*)d_in[13];
    float* out = (float*)d_out;

    // ---- workspace layout (bytes), total ~50 MB ----
    char* p = (char*)d_ws;
    float* xr      = (float*)p;            p += (size_t)2048*1024*4;   // 8 MB  [0,8M)
    bf16*  h_bf    = (bf16*)p;             p += (size_t)2048*1024*2;   // 4 MB  [8,12M)
    bf16*  wqkv    = (bf16*)p;             p += (size_t)1536*1024*2;   // 3 MB  [12,15M)
    bf16*  wproj   = (bf16*)p;             p += (size_t)1024*512*2;    // 1 MB  [15,16M)
    bf16*  wfc     = (bf16*)p;             p += (size_t)4096*1024*2;   // 8 MB  [16,24M)
    bf16*  wcproj  = (bf16*)p;             p += (size_t)1024*4096*2;   // 8 MB  [24,32M)
    float* qkvb_p  = (float*)p;            p += 8192;                  // 6 KB pad
    bf16*  attn_bf = (bf16*)p;             p += (size_t)2048*512*2;    // 2 MB
    bf16*  qkvb    = (bf16*)p;                                         // 6 MB
    bf16*  fc_act  = (bf16*)p;             // 16 MB, overlaps qkvb (dead after attn)
    // proj partials: 2 x 4 MB in the qkvb region (qkvb dead after attn,
    // consumed by reduce<2> before fc writes fc_act there)
    bf16*  proj_part = qkvb;
    // cproj partials: 4 x 4 MB = 16 MB at d_ws[0,16M) (xr/h_bf/wqkv/wproj all
    // dead by cproj time)
    bf16*  cp_part = (bf16*)d_ws;

    conv_all_kernel<<<5121, 256, 0, stream>>>(qkv_w, proj_w, fc_w, cproj_w, qkv_b,
                                              wqkv, wproj, wfc, wcproj, qkvb_p);
    rotary_ln_kernel<<<2048, 256, 0, stream>>>(x, ln1_w, ln1_b, xr, h_bf);
    // qkv: M=2048 N=1536 K=1024 -> grid 12x32 = 384 WGs
    gemm6_kernel<0><<<dim3(12,32,1), 256, 0, stream>>>(h_bf, wqkv, qkvb_p,
                                                       nullptr, qkvb, 1536, 1024, 1024);
    attn_kernel<<<4096, 256, 0, stream>>>(qkvb, rel_pos, attn_bf);
    // proj: M=2048 N=1024 K=512, split-K2 -> grid 8x32x2 = 512 WGs
    gemm6_kernel<3><<<dim3(8,32,2), 256, 0, stream>>>(attn_bf, wproj, nullptr,
                                                      nullptr, proj_part, 1024, 512, 256);
    reduce_kernel<2><<<2048, 256, 0, stream>>>(proj_part, proj_b, xr, out);
    ln_bf16_kernel<<<2048, 256, 0, stream>>>(out, ln2_w, ln2_b, h_bf);
    // fc: M=2048 N=4096 K=1024 -> grid 32x32 = 1024 WGs (4 blocks/CU)
    gemm6_kernel<1><<<dim3(32,32,1), 256, 0, stream>>>(h_bf, wfc, fc_b,
                                                       nullptr, fc_act, 4096, 1024, 1024);
    // cproj: M=2048 N=1024 K=4096, split-K4 -> grid 8x32x4 = 1024 WGs
    gemm6_kernel<3><<<dim3(8,32,4), 256, 0, stream>>>(fc_act, wcproj, nullptr,
                                                      nullptr, cp_part, 1024, 4096, 1024);
    reduce_kernel<4><<<2048, 256, 0, stream>>>(cp_part, cproj_b, out, out);
}

// Round 7
// 145.034 us; speedup vs baseline: 1.1163x; 1.0543x over previous
//
#include <hip/hip_runtime.h>
#include <hip/hip_bf16.h>

// Shapes (fixed): B=2 T=1024 E=1024 H=8 W=31 D=63
// NTOK=2048, H*D=504 (pad 512), 3*H*D=1512 (pad 1536), 4E=4096

typedef __bf16 bf16;
typedef bf16 bf16x8 __attribute__((ext_vector_type(8)));
typedef bf16 bf16x4 __attribute__((ext_vector_type(4)));
typedef bf16 bf16x2 __attribute__((ext_vector_type(2)));
typedef float f32x4 __attribute__((ext_vector_type(4)));

// ---------------- fused rotary + layernorm1 --------------------------------
__global__ __launch_bounds__(256) void rotary_ln_kernel(
    const float* __restrict__ x, const float* __restrict__ w,
    const float* __restrict__ b, float* __restrict__ xr, bf16* __restrict__ Y)
{
    const int row = blockIdx.x;
    const int tid = threadIdx.x;
    float2 xv = *(const float2*)(x + (size_t)row * 512 + tid * 2);
    float i0 = exp2f(-(float)(2*tid)     * 0.025952563241307518f);
    float i1 = exp2f(-(float)(2*tid + 1) * 0.025952563241307518f);
    float a0 = xv.x * i0, a1 = xv.y * i1;
    float s0 = sinf(a0), s1 = sinf(a1);
    float c0 = cosf(a0), c1 = cosf(a1);
    *(float2*)(xr + (size_t)row * 1024 + tid*2)       = make_float2(s0, s1);
    *(float2*)(xr + (size_t)row * 1024 + 512 + tid*2) = make_float2(c0, c1);
    float s  = s0 + s1 + c0 + c1;
    float ss = s0*s0 + s1*s1 + c0*c0 + c1*c1;
    #pragma unroll
    for (int off = 32; off > 0; off >>= 1) {
        s  += __shfl_down(s, off);
        ss += __shfl_down(ss, off);
    }
    __shared__ float rs[4], rss[4];
    int wave = tid >> 6, lane = tid & 63;
    if (lane == 0) { rs[wave] = s; rss[wave] = ss; }
    __syncthreads();
    s  = rs[0] + rs[1] + rs[2] + rs[3];
    ss = rss[0] + rss[1] + rss[2] + rss[3];
    float mu   = s * (1.f / 1024.f);
    float var  = ss * (1.f / 1024.f) - mu * mu;
    float rstd = rsqrtf(var + 1e-5f);
    float2 w0 = *(const float2*)(w + tid*2);
    float2 b0 = *(const float2*)(b + tid*2);
    float2 w1 = *(const float2*)(w + 512 + tid*2);
    float2 b1 = *(const float2*)(b + 512 + tid*2);
    bf16x2 y0, y1;
    y0[0] = (bf16)((s0 - mu) * rstd * w0.x + b0.x);
    y0[1] = (bf16)((s1 - mu) * rstd * w0.y + b0.y);
    y1[0] = (bf16)((c0 - mu) * rstd * w1.x + b1.x);
    y1[1] = (bf16)((c1 - mu) * rstd * w1.y + b1.y);
    *(bf16x2*)(Y + (size_t)row * 1024 + tid*2)       = y0;
    *(bf16x2*)(Y + (size_t)row * 1024 + 512 + tid*2) = y1;
}

// ---------------- layernorm (fp32 in, bf16 out), one block per row --------
__global__ __launch_bounds__(256) void ln_bf16_kernel(
    const float* __restrict__ X, const float* __restrict__ w,
    const float* __restrict__ b, bf16* __restrict__ Y)
{
    int row = blockIdx.x;
    const float4* xp = (const float4*)(X + (size_t)row * 1024);
    float4 xv = xp[threadIdx.x];
    float s  = xv.x + xv.y + xv.z + xv.w;
    float ss = xv.x*xv.x + xv.y*xv.y + xv.z*xv.z + xv.w*xv.w;
    #pragma unroll
    for (int off = 32; off > 0; off >>= 1) {
        s  += __shfl_down(s, off);
        ss += __shfl_down(ss, off);
    }
    __shared__ float rs[4], rss[4];
    int wave = threadIdx.x >> 6, lane = threadIdx.x & 63;
    if (lane == 0) { rs[wave] = s; rss[wave] = ss; }
    __syncthreads();
    s  = rs[0] + rs[1] + rs[2] + rs[3];
    ss = rss[0] + rss[1] + rss[2] + rss[3];
    float mu  = s * (1.f / 1024.f);
    float var = ss * (1.f / 1024.f) - mu * mu;
    float rstd = rsqrtf(var + 1e-5f);
    float4 wv = ((const float4*)w)[threadIdx.x];
    float4 bv = ((const float4*)b)[threadIdx.x];
    bf16 y[4];
    y[0] = (bf16)((xv.x - mu) * rstd * wv.x + bv.x);
    y[1] = (bf16)((xv.y - mu) * rstd * wv.y + bv.y);
    y[2] = (bf16)((xv.z - mu) * rstd * wv.z + bv.z);
    y[3] = (bf16)((xv.w - mu) * rstd * wv.w + bv.w);
    *(uint2*)(Y + (size_t)row * 1024 + threadIdx.x * 4) = *(uint2*)y;
}

// ---------------- fused weight converts (fp32->bf16, zero-pad) + bias pad --
__device__ __forceinline__ void conv_chunk(
    const float* __restrict__ src, bf16* __restrict__ dst,
    int ci, int N, int K, int Kp)
{
    int kpc = Kp >> 3;
    int r  = ci / kpc;
    int kc = (ci - r * kpc) << 3;
    bf16x8 o;
    if (r < N && kc < K) {
        float4 f0 = *(const float4*)(src + (size_t)r * K + kc);
        float4 f1 = *(const float4*)(src + (size_t)r * K + kc + 4);
        o[0]=(bf16)f0.x; o[1]=(bf16)f0.y; o[2]=(bf16)f0.z; o[3]=(bf16)f0.w;
        o[4]=(bf16)f1.x; o[5]=(bf16)f1.y; o[6]=(bf16)f1.z; o[7]=(bf16)f1.w;
    } else {
        #pragma unroll
        for (int j = 0; j < 8; ++j) o[j] = (bf16)0.f;
    }
    *(bf16x8*)(dst + (size_t)r * Kp + kc) = o;
}

__global__ __launch_bounds__(256) void conv_all_kernel(
    const float* __restrict__ qkv_w, const float* __restrict__ proj_w,
    const float* __restrict__ fc_w,  const float* __restrict__ cproj_w,
    const float* __restrict__ qkv_b,
    bf16* __restrict__ wqkv, bf16* __restrict__ wproj,
    bf16* __restrict__ wfc,  bf16* __restrict__ wcproj,
    float* __restrict__ qkvb_p)
{
    if (blockIdx.x == 5120) {
        for (int i = threadIdx.x; i < 1536; i += 256)
            qkvb_p[i] = (i < 1512) ? qkv_b[i] : 0.f;
        return;
    }
    int idx = blockIdx.x * 256 + threadIdx.x;
    if      (idx < 196608)  conv_chunk(qkv_w,   wqkv,   idx,          1512, 1024, 1024);
    else if (idx < 262144)  conv_chunk(proj_w,  wproj,  idx - 196608, 1024,  504,  512);
    else if (idx < 786432)  conv_chunk(fc_w,    wfc,    idx - 262144, 4096, 1024, 1024);
    else                    conv_chunk(cproj_w, wcproj, idx - 786432, 1024, 4096, 4096);
}

// ---------------- waitcnt / barrier helpers --------------------------------
template<int N> __device__ __forceinline__ void vmwait()
{
    if constexpr      (N==0) asm volatile("s_waitcnt vmcnt(0)" ::: "memory");
    else if constexpr (N==4) asm volatile("s_waitcnt vmcnt(4)" ::: "memory");
    else if constexpr (N==6) asm volatile("s_waitcnt vmcnt(6)" ::: "memory");
}
__device__ __forceinline__ void lgkmwait0()
{
    asm volatile("s_waitcnt lgkmcnt(0)" ::: "memory");
}
__device__ __forceinline__ void hw_barrier()
{
    asm volatile("s_barrier" ::: "memory");
}

__device__ __forceinline__ void gload16(const char* src, char* ldsdst)
{
    __builtin_amdgcn_global_load_lds(
        (const __attribute__((address_space(1))) void*)src,
        (__attribute__((address_space(3))) void*)ldsdst, 16, 0, 0);
}

__device__ __forceinline__ float gelu_exact(float v)
{
    return 0.5f * v * (1.f + erff(v * 0.70710678118654752f));
}

// ---------------- gemm8: 128x256 tile, 8 waves, counted-vmcnt pipeline -----
// C = A[M,Kp] @ W[Np,Kp]^T (+bias). BM=128, BN=256, BK=64, waves 2Mx4N
// (64x64 out/wave, acc[4][4]).  LDS = A dbuf 2x16KB + B tbuf 3x32KB = 128KB
// (1 block/CU, 8 waves).  Stage at top of iter: A(t+1), B(t+2); one barrier
// per tile with counted vmcnt(4) (B(t+2) stays in flight across it — T3/T4).
// lgkmcnt(0) before barrier: all ds_reads of tile t complete, so stages
// issued next iter can't corrupt (reuse distance: A 2 barriers, B 3).
// Rows are 128B -> T2 XOR swizzle slot^=(row&7), applied to pre-swizzled
// GLOBAL source (LDS linear, rule 21) and to ds_read addresses.
// EPI: 1 = gelu->bf16, 3 = bf16 partial (no bias, z-strided)
template<int EPI>
__global__ __launch_bounds__(512, 2) void gemm8_kernel(
    const bf16* __restrict__ A, const bf16* __restrict__ Wt,
    const float* __restrict__ bias, bf16* __restrict__ Cb,
    int N, int Kp, int ksplit)
{
    __shared__ __align__(16) char lds[131072];  // A: 2x16K @0, B: 3x32K @32768

    const int tid  = threadIdx.x;       // 0..511
    const int w    = tid >> 6;
    const int lane = tid & 63;
    const int wm   = w >> 2;            // 0..1
    const int wn   = w & 3;             // 0..3
    const int rl   = lane & 15;
    const int lh   = lane >> 4;         // 0..3

    // bijective XCD-chunked swizzle (nwg % 8 == 0 at all call sites)
    const int gx = gridDim.x, gy = gridDim.y;
    const int nwg = gx * gy * gridDim.z;
    const int chunk = nwg >> 3;
    int id = (blockIdx.z * gy + blockIdx.y) * gx + blockIdx.x;
    int sw = (id & 7) * chunk + (id >> 3);
    const int bx = sw % gx;
    const int t2 = sw / gx;
    const int by = t2 % gy;
    const int bz = t2 / gy;

    const int row0 = by * 128;
    const int col0 = bx * 256;
    const size_t strideBy = (size_t)Kp * 2;
    const size_t kz = (size_t)bz * ksplit * 2;
    const char* Abase = (const char*)A  + (size_t)row0 * strideBy + kz;
    const char* Wbase = (const char*)Wt + (size_t)col0 * strideBy + kz;

    // pre-swizzled global source offsets; LDS dest stays linear (rule 21)
    size_t srcA[2], srcB[4];
    #pragma unroll
    for (int i = 0; i < 2; ++i) {
        int ls = i * 512 + tid;                 // A slot 0..1023 (8/row)
        int r = ls >> 3, s = ls & 7;
        srcA[i] = (size_t)r * strideBy + (size_t)((s ^ (r & 7)) << 4);
    }
    #pragma unroll
    for (int i = 0; i < 4; ++i) {
        int ls = i * 512 + tid;                 // B slot 0..2047
        int r = ls >> 3, s = ls & 7;
        srcB[i] = (size_t)r * strideBy + (size_t)((s ^ (r & 7)) << 4);
    }

    auto STAGE_A = [&](int buf, int kt) {
        const char* ab = Abase + (size_t)kt * 128;
        char* d = &lds[buf * 16384];
        #pragma unroll
        for (int i = 0; i < 2; ++i)
            gload16(ab + srcA[i], d + (i * 512 + tid) * 16);
    };
    auto STAGE_B = [&](int buf, int kt) {
        const char* wb = Wbase + (size_t)kt * 128;
        char* d = &lds[32768 + buf * 32768];
        #pragma unroll
        for (int i = 0; i < 4; ++i)
            gload16(wb + srcB[i], d + (i * 512 + tid) * 16);
    };

    f32x4 acc[4][4] = {};
    const int niter = ksplit >> 6;      // BK=64; all call sites >= 3

    STAGE_A(0, 0);
    STAGE_B(0, 0);
    STAGE_B(1, 1);
    vmwait<4>();                        // A0+B0 landed; B1 (4) in flight
    hw_barrier();

    int cb3 = 0, sb3 = 2;               // B compute / stage buffer indices
    for (int kt = 0; kt < niter; ++kt) {
        if (kt + 1 < niter) STAGE_A((kt + 1) & 1, kt + 1);
        if (kt + 2 < niter) STAGE_B(sb3, kt + 2);

        const char* pA = &lds[(kt & 1) * 16384];
        const char* pB = &lds[32768 + cb3 * 32768];
        bf16x8 af[4][2], bq[4][2];
        #pragma unroll
        for (int mi = 0; mi < 4; ++mi) {
            int ar = wm * 64 + mi * 16 + rl;
            #pragma unroll
            for (int ks = 0; ks < 2; ++ks)
                af[mi][ks] = *(const bf16x8*)
                    (pA + ar * 128 + (((ks * 4 + lh) ^ (ar & 7)) << 4));
        }
        #pragma unroll
        for (int nj = 0; nj < 4; ++nj) {
            int br = wn * 64 + nj * 16 + rl;
            #pragma unroll
            for (int ks = 0; ks < 2; ++ks)
                bq[nj][ks] = *(const bf16x8*)
                    (pB + br * 128 + (((ks * 4 + lh) ^ (br & 7)) << 4));
        }
        __builtin_amdgcn_s_setprio(1);
        #pragma unroll
        for (int ks = 0; ks < 2; ++ks)
            #pragma unroll
            for (int mi = 0; mi < 4; ++mi)
                #pragma unroll
                for (int nj = 0; nj < 4; ++nj)
                    acc[mi][nj] = __builtin_amdgcn_mfma_f32_16x16x32_bf16(
                        af[mi][ks], bq[nj][ks], acc[mi][nj], 0, 0, 0);
        __builtin_amdgcn_s_setprio(0);

        if (kt + 1 < niter) {
            lgkmwait0();                        // my tile-kt ds_reads done
            if (kt + 2 < niter) vmwait<4>();    // A(t+1),B(t+1) landed; B(t+2) flying
            else                vmwait<0>();    // tail: drain everything
            hw_barrier();
        }
        cb3 = (cb3 == 2) ? 0 : cb3 + 1;
        sb3 = (sb3 == 2) ? 0 : sb3 + 1;
    }

    // C/D layout: col = lane&15, row = (lane>>4)*4 + reg   [m89/m91]
    const int rq = lh * 4;
    bf16* Cbz = Cb;
    if (EPI == 3) Cbz += (size_t)bz * 2048 * N;
    #pragma unroll
    for (int mi = 0; mi < 4; ++mi) {
        #pragma unroll
        for (int rj = 0; rj < 4; ++rj) {
            int row = row0 + wm * 64 + mi * 16 + rq + rj;
            #pragma unroll
            for (int nj = 0; nj < 4; ++nj) {
                int col = col0 + wn * 64 + nj * 16 + rl;
                float c = acc[mi][nj][rj];
                size_t off = (size_t)row * N + col;
                if (EPI == 1) Cbz[off] = (bf16)gelu_exact(c + bias[col]);
                else          Cbz[off] = (bf16)c;
            }
        }
    }
}

// ---------------- gemm6: 64x128 tile, 4 waves, ping-pong (small GEMMs) -----
template<int EPI>
__global__ __launch_bounds__(256, 4) void gemm6_kernel(
    const bf16* __restrict__ A, const bf16* __restrict__ Wt,
    const float* __restrict__ bias,
    float* Cf, bf16* Cb, int N, int Kp, int ksplit)
{
    __shared__ __align__(16) char lds[2][12288];   // per buf: A 4KB | B 8KB

    const int tid  = threadIdx.x;
    const int w    = tid >> 6;
    const int lane = tid & 63;

    const int gx = gridDim.x, gy = gridDim.y;
    const int nwg = gx * gy * gridDim.z;
    const int chunk = nwg >> 3;
    int id = (blockIdx.z * gy + blockIdx.y) * gx + blockIdx.x;
    int sw = (id & 7) * chunk + (id >> 3);
    const int bx = sw % gx;
    const int t2 = sw / gx;
    const int by = t2 % gy;
    const int bz = t2 / gy;

    const int row0 = by * 64;
    const int col0 = bx * 128;
    const int wr = (w >> 1) * 32;
    const int wc = (w & 1) * 64;
    const int rl = lane & 15;
    const int kb16 = (lane >> 4) * 16;

    const size_t strideBy = (size_t)Kp * 2;
    const size_t kz = (size_t)bz * ksplit * 2;
    const char* Abase = (const char*)A  + (size_t)row0 * strideBy + kz;
    const char* Wbase = (const char*)Wt + (size_t)col0 * strideBy + kz;

    const size_t srcA0 = (size_t)(tid >> 2) * strideBy + (tid & 3) * 16;
    size_t srcB[2];
    #pragma unroll
    for (int i = 0; i < 2; ++i) {
        int o = (i * 256 + tid) * 16;
        srcB[i] = (size_t)(o >> 6) * strideBy + (o & 63);
    }

    f32x4 acc[2][4] = {};

    auto STAGE = [&](int buf, int kt) {
        const char* ab = Abase + (size_t)kt * 64;
        const char* wb = Wbase + (size_t)kt * 64;
        gload16(ab + srcA0, &lds[buf][0] + tid * 16);
        #pragma unroll
        for (int i = 0; i < 2; ++i)
            gload16(wb + srcB[i], &lds[buf][4096] + (i * 256 + tid) * 16);
    };

    const int niter = ksplit >> 5;      // BK = 32
    STAGE(0, 0);
    __syncthreads();
    for (int kt = 0; kt < niter; ++kt) {
        if (kt + 1 < niter)
            STAGE((kt + 1) & 1, kt + 1);
        const char* base = lds[kt & 1];
        bf16x8 af[2], bfr[4];
        #pragma unroll
        for (int mi = 0; mi < 2; ++mi)
            af[mi] = *(const bf16x8*)(base + ((wr + mi*16 + rl) << 6) + kb16);
        #pragma unroll
        for (int nj = 0; nj < 4; ++nj)
            bfr[nj] = *(const bf16x8*)(base + 4096 + ((wc + nj*16 + rl) << 6) + kb16);
        __builtin_amdgcn_s_setprio(1);
        #pragma unroll
        for (int mi = 0; mi < 2; ++mi)
            #pragma unroll
            for (int nj = 0; nj < 4; ++nj)
                acc[mi][nj] = __builtin_amdgcn_mfma_f32_16x16x32_bf16(
                    af[mi], bfr[nj], acc[mi][nj], 0, 0, 0);
        __builtin_amdgcn_s_setprio(0);
        __syncthreads();
    }

    const int rq = (lane >> 4) * 4;
    bf16* Cbz = Cb;
    if (EPI == 3) Cbz += (size_t)bz * 2048 * N;
    #pragma unroll
    for (int mi = 0; mi < 2; ++mi) {
        #pragma unroll
        for (int rj = 0; rj < 4; ++rj) {
            int row = row0 + wr + mi*16 + rq + rj;
            #pragma unroll
            for (int nj = 0; nj < 4; ++nj) {
                int col = col0 + wc + nj*16 + rl;
                float c = acc[mi][nj][rj];
                if (EPI != 3) c += bias[col];
                size_t off = (size_t)row * N + col;
                if (EPI == 0)      Cb[off]  = (bf16)c;
                else               Cbz[off] = (bf16)c;
            }
        }
    }
}

// ---------------- split-K reducer: out = R + bias + sum(parts) -------------
template<int P>
__global__ __launch_bounds__(256) void reduce_kernel(
    const bf16* __restrict__ parts, const float* __restrict__ bias,
    const float* R, float* out)
{
    int row = blockIdx.x;
    int c = threadIdx.x * 4;
    size_t off = (size_t)row * 1024 + c;
    float4 bv = *(const float4*)(bias + c);
    float4 o = *(const float4*)(R + off);
    o.x += bv.x; o.y += bv.y; o.z += bv.z; o.w += bv.w;
    #pragma unroll
    for (int p = 0; p < P; ++p) {
        bf16x4 v = *(const bf16x4*)(parts + (size_t)p * 2048 * 1024 + off);
        o.x += (float)v[0]; o.y += (float)v[1];
        o.z += (float)v[2]; o.w += (float)v[3];
    }
    *(float4*)(out + off) = o;
}

// ---------------- windowed attention, one wave per (b,h,t) token ----------
__global__ __launch_bounds__(256) void attn_kernel(
    const bf16* __restrict__ qkv, const float* __restrict__ rel_pos,
    bf16* __restrict__ outp)
{
    __shared__ float sbias[64*65];
    __shared__ float kmw[4][3][64];
    for (int i = threadIdx.x; i < 63*63; i += 256) {
        int d = i / 63, v = i - d*63;
        sbias[d*65 + v] = rel_pos[((d + 32) % 63) * 63 + v];
    }
    __syncthreads();
    const int wave = threadIdx.x >> 6;
    const int lane = threadIdx.x & 63;
    const int tk  = blockIdx.x * 4 + wave;
    const int row = tk >> 3;
    const int h   = tk & 7;
    const bf16* base = qkv + (size_t)row * 1536 + h * 63;
    float q_own = 0.f, k_own = 0.f, v_own = 0.f;
    if (lane < 63) {
        q_own = (float)base[lane];
        k_own = (float)base[504 + lane];
        v_own = (float)base[1008 + lane];
    }
    float m = -1e30f;
    for (int d = 0; d < 63; ++d) {
        float qd = __shfl(q_own, d);
        m = fmaxf(m, fmaf(qd, k_own, sbias[d*65 + lane]));
    }
    float Z = 0.f;
    for (int d = 0; d < 63; ++d) {
        float qd = __shfl(q_own, d);
        Z += __expf(fmaf(qd, k_own, sbias[d*65 + lane]) - m);
    }
    kmw[wave][0][lane] = k_own;
    kmw[wave][1][lane] = m;
    kmw[wave][2][lane] = v_own / Z;
    float acc = 0.f;
    for (int v = 0; v < 63; ++v) {
        float s = fmaf(q_own, kmw[wave][0][v], sbias[lane*65 + v]) - kmw[wave][1][v];
        acc += __expf(s) * kmw[wave][2][v];
    }
    if (lane < 63)
        outp[(size_t)row * 512 + h*63 + lane] = (bf16)acc;
    if (h == 7 && lane == 63) {
        #pragma unroll
        for (int j = 0; j < 8; ++j)
            outp[(size_t)row * 512 + 504 + j] = (bf16)0.f;
    }
}

extern "C" void kernel_launch(void* const* d_in, const int* in_sizes, int n_in,
                              void* d_out, int out_size, void* d_ws, size_t ws_size,
                              hipStream_t stream)
{
    const float* x       = (const float*)d_in[0];
    const float* ln1_w   = (const float*)d_in[1];
    const float* ln1_b   = (const float*)d_in[2];
    const float* qkv_w   = (const float*)d_in[3];
    const float* qkv_b   = (const float*)d_in[4];
    const float* rel_pos = (const float*)d_in[5];
    const float* proj_w  = (const float*)d_in[6];
    const float* proj_b  = (const float*)d_in[7];
    const float* ln2_w   = (const float*)d_in[8];
    const float* ln2_b   = (const float*)d_in[9];
    const float* fc_w    = (const float*)d_in[10];
    const float* fc_b    = (const float*)d_in[11];
    const float* cproj_w = (const float*)d_in[12];
    const float* cproj_b = (const float*)d_in[13];
    float* out = (float*)d_out;

    // ---- workspace layout (bytes), total ~50 MB ----
    char* p = (char*)d_ws;
    float* xr      = (float*)p;            p += (size_t)2048*1024*4;   // 8 MB  [0,8M)
    bf16*  h_bf    = (bf16*)p;             p += (size_t)2048*1024*2;   // 4 MB  [8,12M)
    bf16*  wqkv    = (bf16*)p;             p += (size_t)1536*1024*2;   // 3 MB
    bf16*  wproj   = (bf16*)p;             p += (size_t)1024*512*2;    // 1 MB
    bf16*  wfc     = (bf16*)p;             p += (size_t)4096*1024*2;   // 8 MB
    bf16*  wcproj  = (bf16*)p;             p += (size_t)1024*4096*2;   // 8 MB
    float* qkvb_p  = (float*)p;            p += 8192;                  // 6 KB pad
    bf16*  attn_bf = (bf16*)p;             p += (size_t)2048*512*2;    // 2 MB
    bf16*  qkvb    = (bf16*)p;                                         // 6 MB
    bf16*  fc_act  = (bf16*)p;             // 16 MB, overlaps qkvb (dead after attn)
    bf16*  proj_part = qkvb;               // 2 x 4 MB (dead before fc writes fc_act)
    bf16*  cp_part = (bf16*)d_ws;          // 4 x 4 MB over xr/h_bf/wqkv/wproj (dead)

    conv_all_kernel<<<5121, 256, 0, stream>>>(qkv_w, proj_w, fc_w, cproj_w, qkv_b,
                                              wqkv, wproj, wfc, wcproj, qkvb_p);
    rotary_ln_kernel<<<2048, 256, 0, stream>>>(x, ln1_w, ln1_b, xr, h_bf);
    // qkv: M=2048 N=1536 K=1024 -> 12x32 = 384 WGs
    gemm6_kernel<0><<<dim3(12,32,1), 256, 0, stream>>>(h_bf, wqkv, qkvb_p,
                                                       nullptr, qkvb, 1536, 1024, 1024);
    attn_kernel<<<4096, 256, 0, stream>>>(qkvb, rel_pos, attn_bf);
    // proj: M=2048 N=1024 K=512, split-K2 -> 8x32x2 = 512 WGs
    gemm6_kernel<3><<<dim3(8,32,2), 256, 0, stream>>>(attn_bf, wproj, nullptr,
                                                      nullptr, proj_part, 1024, 512, 256);
    reduce_kernel<2><<<2048, 256, 0, stream>>>(proj_part, proj_b, xr, out);
    ln_bf16_kernel<<<2048, 256, 0, stream>>>(out, ln2_w, ln2_b, h_bf);
    // fc: M=2048 N=4096 K=1024 -> gemm8 16x16 = 256 WGs (1/CU)
    gemm8_kernel<1><<<dim3(16,16,1), 512, 0, stream>>>(h_bf, wfc, fc_b,
                                                       fc_act, 4096, 1024, 1024);
    // cproj: M=2048 N=1024 K=4096, split-K4 -> gemm8 4x16x4 = 256 WGs
    gemm8_kernel<3><<<dim3(4,16,4), 512, 0, stream>>>(fc_act, wcproj, nullptr,
                                                      cp_part, 1024, 4096, 1024);
    reduce_kernel<4><<<2048, 256, 0, stream>>>(cp_part, cproj_b, out, out);
}

// Round 8
// 144.468 us; speedup vs baseline: 1.1206x; 1.0039x over previous
//
#include <hip/hip_runtime.h>
#include <hip/hip_bf16.h>

// Shapes (fixed): B=2 T=1024 E=1024 H=8 W=31 D=63
// NTOK=2048, H*D=504 (pad 512), 3*H*D=1512 (pad 1536), 4E=4096

typedef __bf16 bf16;
typedef bf16 bf16x8 __attribute__((ext_vector_type(8)));
typedef bf16 bf16x4 __attribute__((ext_vector_type(4)));
typedef bf16 bf16x2 __attribute__((ext_vector_type(2)));
typedef float f32x4 __attribute__((ext_vector_type(4)));

// ---------------- fused rotary + layernorm1 --------------------------------
__global__ __launch_bounds__(256) void rotary_ln_kernel(
    const float* __restrict__ x, const float* __restrict__ w,
    const float* __restrict__ b, float* __restrict__ xr, bf16* __restrict__ Y)
{
    const int row = blockIdx.x;
    const int tid = threadIdx.x;
    float2 xv = *(const float2*)(x + (size_t)row * 512 + tid * 2);
    float i0 = exp2f(-(float)(2*tid)     * 0.025952563241307518f);
    float i1 = exp2f(-(float)(2*tid + 1) * 0.025952563241307518f);
    float a0 = xv.x * i0, a1 = xv.y * i1;
    float s0 = sinf(a0), s1 = sinf(a1);
    float c0 = cosf(a0), c1 = cosf(a1);
    *(float2*)(xr + (size_t)row * 1024 + tid*2)       = make_float2(s0, s1);
    *(float2*)(xr + (size_t)row * 1024 + 512 + tid*2) = make_float2(c0, c1);
    float s  = s0 + s1 + c0 + c1;
    float ss = s0*s0 + s1*s1 + c0*c0 + c1*c1;
    #pragma unroll
    for (int off = 32; off > 0; off >>= 1) {
        s  += __shfl_down(s, off);
        ss += __shfl_down(ss, off);
    }
    __shared__ float rs[4], rss[4];
    int wave = tid >> 6, lane = tid & 63;
    if (lane == 0) { rs[wave] = s; rss[wave] = ss; }
    __syncthreads();
    s  = rs[0] + rs[1] + rs[2] + rs[3];
    ss = rss[0] + rss[1] + rss[2] + rss[3];
    float mu   = s * (1.f / 1024.f);
    float var  = ss * (1.f / 1024.f) - mu * mu;
    float rstd = rsqrtf(var + 1e-5f);
    float2 w0 = *(const float2*)(w + tid*2);
    float2 b0 = *(const float2*)(b + tid*2);
    float2 w1 = *(const float2*)(w + 512 + tid*2);
    float2 b1 = *(const float2*)(b + 512 + tid*2);
    bf16x2 y0, y1;
    y0[0] = (bf16)((s0 - mu) * rstd * w0.x + b0.x);
    y0[1] = (bf16)((s1 - mu) * rstd * w0.y + b0.y);
    y1[0] = (bf16)((c0 - mu) * rstd * w1.x + b1.x);
    y1[1] = (bf16)((c1 - mu) * rstd * w1.y + b1.y);
    *(bf16x2*)(Y + (size_t)row * 1024 + tid*2)       = y0;
    *(bf16x2*)(Y + (size_t)row * 1024 + 512 + tid*2) = y1;
}

// ---------------- layernorm (fp32 in, bf16 out), one block per row --------
__global__ __launch_bounds__(256) void ln_bf16_kernel(
    const float* __restrict__ X, const float* __restrict__ w,
    const float* __restrict__ b, bf16* __restrict__ Y)
{
    int row = blockIdx.x;
    const float4* xp = (const float4*)(X + (size_t)row * 1024);
    float4 xv = xp[threadIdx.x];
    float s  = xv.x + xv.y + xv.z + xv.w;
    float ss = xv.x*xv.x + xv.y*xv.y + xv.z*xv.z + xv.w*xv.w;
    #pragma unroll
    for (int off = 32; off > 0; off >>= 1) {
        s  += __shfl_down(s, off);
        ss += __shfl_down(ss, off);
    }
    __shared__ float rs[4], rss[4];
    int wave = threadIdx.x >> 6, lane = threadIdx.x & 63;
    if (lane == 0) { rs[wave] = s; rss[wave] = ss; }
    __syncthreads();
    s  = rs[0] + rs[1] + rs[2] + rs[3];
    ss = rss[0] + rss[1] + rss[2] + rss[3];
    float mu  = s * (1.f / 1024.f);
    float var = ss * (1.f / 1024.f) - mu * mu;
    float rstd = rsqrtf(var + 1e-5f);
    float4 wv = ((const float4*)w)[threadIdx.x];
    float4 bv = ((const float4*)b)[threadIdx.x];
    bf16 y[4];
    y[0] = (bf16)((xv.x - mu) * rstd * wv.x + bv.x);
    y[1] = (bf16)((xv.y - mu) * rstd * wv.y + bv.y);
    y[2] = (bf16)((xv.z - mu) * rstd * wv.z + bv.z);
    y[3] = (bf16)((xv.w - mu) * rstd * wv.w + bv.w);
    *(uint2*)(Y + (size_t)row * 1024 + threadIdx.x * 4) = *(uint2*)y;
}

// ---------------- fused weight converts (fp32->bf16, zero-pad) + bias pad --
__device__ __forceinline__ void conv_chunk(
    const float* __restrict__ src, bf16* __restrict__ dst,
    int ci, int N, int K, int Kp)
{
    int kpc = Kp >> 3;
    int r  = ci / kpc;
    int kc = (ci - r * kpc) << 3;
    bf16x8 o;
    if (r < N && kc < K) {
        float4 f0 = *(const float4*)(src + (size_t)r * K + kc);
        float4 f1 = *(const float4*)(src + (size_t)r * K + kc + 4);
        o[0]=(bf16)f0.x; o[1]=(bf16)f0.y; o[2]=(bf16)f0.z; o[3]=(bf16)f0.w;
        o[4]=(bf16)f1.x; o[5]=(bf16)f1.y; o[6]=(bf16)f1.z; o[7]=(bf16)f1.w;
    } else {
        #pragma unroll
        for (int j = 0; j < 8; ++j) o[j] = (bf16)0.f;
    }
    *(bf16x8*)(dst + (size_t)r * Kp + kc) = o;
}

__global__ __launch_bounds__(256) void conv_all_kernel(
    const float* __restrict__ qkv_w, const float* __restrict__ proj_w,
    const float* __restrict__ fc_w,  const float* __restrict__ cproj_w,
    const float* __restrict__ qkv_b,
    bf16* __restrict__ wqkv, bf16* __restrict__ wproj,
    bf16* __restrict__ wfc,  bf16* __restrict__ wcproj,
    float* __restrict__ qkvb_p)
{
    if (blockIdx.x == 5120) {
        for (int i = threadIdx.x; i < 1536; i += 256)
            qkvb_p[i] = (i < 1512) ? qkv_b[i] : 0.f;
        return;
    }
    int idx = blockIdx.x * 256 + threadIdx.x;
    if      (idx < 196608)  conv_chunk(qkv_w,   wqkv,   idx,          1512, 1024, 1024);
    else if (idx < 262144)  conv_chunk(proj_w,  wproj,  idx - 196608, 1024,  504,  512);
    else if (idx < 786432)  conv_chunk(fc_w,    wfc,    idx - 262144, 4096, 1024, 1024);
    else                    conv_chunk(cproj_w, wcproj, idx - 786432, 1024, 4096, 4096);
}

// ---------------- waitcnt / barrier helpers --------------------------------
template<int N> __device__ __forceinline__ void vmwait()
{
    if constexpr      (N==0) asm volatile("s_waitcnt vmcnt(0)" ::: "memory");
    else if constexpr (N==6) asm volatile("s_waitcnt vmcnt(6)" ::: "memory");
}
__device__ __forceinline__ void lgkmwait0()
{
    asm volatile("s_waitcnt lgkmcnt(0)" ::: "memory");
}
__device__ __forceinline__ void hw_barrier()
{
    asm volatile("s_barrier" ::: "memory");
}
__device__ __forceinline__ void gload16(const char* src, char* ldsdst)
{
    __builtin_amdgcn_global_load_lds(
        (const __attribute__((address_space(1))) void*)src,
        (__attribute__((address_space(3))) void*)ldsdst, 16, 0, 0);
}
__device__ __forceinline__ float gelu_exact(float v)
{
    return 0.5f * v * (1.f + erff(v * 0.70710678118654752f));
}

// ---------------- gemm8p: 128x256, 8 waves, 8-phase interleaved pipeline ---
// C = A[M,Kp] @ W[Np,Kp]^T (+bias). BM=128 BN=256 BK=64, waves 2Mx4N
// (64x64/wave). LDS 112KB: A 3 bufs x16KB @0; B row-half0 2 bufs @49152,
// row-half1 2 bufs @81920. Each wave's B frags live in ONE half (wn>>1).
// Per K-tile: 4 phases, each {ds_reads; lgkm0; s_barrier; setprio; 8 MFMA}.
// vmcnt(6)+barrier once at iter top (tiles t+1,t+2 partially in flight).
// Stage A(t+2) at phase0, B(t+2) at phase3 (WAR: slot reads retired at the
// lgkm0+barrier of the prior iter's phase2). Last iter peeled (vmcnt(0)).
// Rows 128B, swizzle slot^=(row&7) on pre-swizzled global source + ds_read
// (R7-proven: SQ_LDS_BANK_CONFLICT = 0).
// EPI: 1 = gelu->bf16, 3 = bf16 partial (no bias, z-strided)
template<int EPI>
__global__ __launch_bounds__(512, 2) void gemm8p_kernel(
    const bf16* __restrict__ A, const bf16* __restrict__ Wt,
    const float* __restrict__ bias, bf16* __restrict__ Cb,
    int N, int Kp, int ksplit)
{
    __shared__ __align__(16) char lds[114688];

    const int tid  = threadIdx.x;       // 0..511
    const int w    = tid >> 6;
    const int lane = tid & 63;
    const int wm   = w >> 2;            // 0..1
    const int wn   = w & 3;             // 0..3
    const int rl   = lane & 15;
    const int lh   = lane >> 4;         // 0..3

    // bijective XCD-chunked swizzle (nwg % 8 == 0 at all call sites)
    const int gx = gridDim.x, gy = gridDim.y;
    const int nwg = gx * gy * gridDim.z;
    const int chunk = nwg >> 3;
    int id = (blockIdx.z * gy + blockIdx.y) * gx + blockIdx.x;
    int sw = (id & 7) * chunk + (id >> 3);
    const int bx = sw % gx;
    const int t2 = sw / gx;
    const int by = t2 % gy;
    const int bz = t2 / gy;

    const int row0 = by * 128;
    const int col0 = bx * 256;
    const size_t strideBy = (size_t)Kp * 2;
    const size_t kz = (size_t)bz * ksplit * 2;
    const char* Abase = (const char*)A  + (size_t)row0 * strideBy + kz;
    const char* Wbase = (const char*)Wt + (size_t)col0 * strideBy + kz;

    // pre-swizzled global source offsets (LDS dest linear, rule 21)
    size_t aoff[2], boff[4];
    #pragma unroll
    for (int i = 0; i < 2; ++i) {
        int ls = i * 512 + tid;                 // A slot 0..1023 (8/row)
        int r = ls >> 3, s = ls & 7;
        aoff[i] = (size_t)r * strideBy + (size_t)((s ^ (r & 7)) << 4);
    }
    #pragma unroll
    for (int i = 0; i < 4; ++i) {
        int ls = i * 512 + tid;                 // B slot 0..2047
        int r = ls >> 3, s = ls & 7;
        boff[i] = (size_t)r * strideBy + (size_t)((s ^ (r & 7)) << 4);
    }

    auto STAGE_A = [&](int t) {
        const char* g = Abase + (size_t)t * 128;
        char* d = &lds[(t % 3) * 16384];
        #pragma unroll
        for (int i = 0; i < 2; ++i)
            gload16(g + aoff[i], d + (i * 512 + tid) * 16);
    };
    auto STAGE_B = [&](int t) {
        const char* g = Wbase + (size_t)t * 128;
        #pragma unroll
        for (int i = 0; i < 4; ++i) {
            char* d = &lds[49152 + (i >> 1) * 32768 + (t & 1) * 16384];
            gload16(g + boff[i], d + ((i & 1) * 512 + tid) * 16);
        }
    };

    const int bhalf = wn >> 1;              // which B row-half this wave uses
    const int brow  = (wn & 1) * 64;        // local row base within half

    f32x4 acc[4][4] = {};
    const int nt = ksplit >> 6;             // all call sites: nt = 16

    // prologue: queue order [A(0), B(0), A(1), B(1)] = 12 loads/thread
    STAGE_A(0); STAGE_B(0); STAGE_A(1); STAGE_B(1);

    for (int t = 0; t < nt; ++t) {
        if (t == nt - 1) vmwait<0>(); else vmwait<6>();
        hw_barrier();                       // ALL waves' tile-t loads landed
        const char* pA = &lds[(t % 3) * 16384];
        const char* pB = &lds[49152 + bhalf * 32768 + (t & 1) * 16384];

        bf16x8 af0[4], af1[4], bq0[4], bq1[4];
        // ---- phase 0: reads af[*][ks0], bq[0,1][ks0]; stage A(t+2); MFMA q00
        #pragma unroll
        for (int mi = 0; mi < 4; ++mi) {
            int ar = wm * 64 + mi * 16 + rl;
            af0[mi] = *(const bf16x8*)(pA + ar * 128 + ((lh ^ (ar & 7)) << 4));
        }
        #pragma unroll
        for (int nj = 0; nj < 2; ++nj) {
            int br = brow + nj * 16 + rl;
            bq0[nj] = *(const bf16x8*)(pB + br * 128 + ((lh ^ (br & 7)) << 4));
        }
        if (t + 2 < nt) STAGE_A(t + 2);
        lgkmwait0();
        hw_barrier();
        __builtin_amdgcn_s_setprio(1);
        #pragma unroll
        for (int mi = 0; mi < 4; ++mi)
            #pragma unroll
            for (int nj = 0; nj < 2; ++nj)
                acc[mi][nj] = __builtin_amdgcn_mfma_f32_16x16x32_bf16(
                    af0[mi], bq0[nj], acc[mi][nj], 0, 0, 0);
        __builtin_amdgcn_s_setprio(0);

        // ---- phase 1: reads bq[2,3][ks0], bq[0,1][ks1]; MFMA q01
        #pragma unroll
        for (int nj = 2; nj < 4; ++nj) {
            int br = brow + nj * 16 + rl;
            bq0[nj] = *(const bf16x8*)(pB + br * 128 + ((lh ^ (br & 7)) << 4));
        }
        #pragma unroll
        for (int nj = 0; nj < 2; ++nj) {
            int br = brow + nj * 16 + rl;
            bq1[nj] = *(const bf16x8*)(pB + br * 128 + (((4 + lh) ^ (br & 7)) << 4));
        }
        lgkmwait0();
        hw_barrier();
        __builtin_amdgcn_s_setprio(1);
        #pragma unroll
        for (int mi = 0; mi < 4; ++mi)
            #pragma unroll
            for (int nj = 2; nj < 4; ++nj)
                acc[mi][nj] = __builtin_amdgcn_mfma_f32_16x16x32_bf16(
                    af0[mi], bq0[nj], acc[mi][nj], 0, 0, 0);
        __builtin_amdgcn_s_setprio(0);

        // ---- phase 2: reads af[*][ks1], bq[2,3][ks1]; MFMA q10
        #pragma unroll
        for (int mi = 0; mi < 4; ++mi) {
            int ar = wm * 64 + mi * 16 + rl;
            af1[mi] = *(const bf16x8*)(pA + ar * 128 + (((4 + lh) ^ (ar & 7)) << 4));
        }
        #pragma unroll
        for (int nj = 2; nj < 4; ++nj) {
            int br = brow + nj * 16 + rl;
            bq1[nj] = *(const bf16x8*)(pB + br * 128 + (((4 + lh) ^ (br & 7)) << 4));
        }
        lgkmwait0();
        hw_barrier();
        __builtin_amdgcn_s_setprio(1);
        #pragma unroll
        for (int mi = 0; mi < 4; ++mi)
            #pragma unroll
            for (int nj = 0; nj < 2; ++nj)
                acc[mi][nj] = __builtin_amdgcn_mfma_f32_16x16x32_bf16(
                    af1[mi], bq1[nj], acc[mi][nj], 0, 0, 0);
        __builtin_amdgcn_s_setprio(0);

        // ---- phase 3: stage B(t+2); MFMA q11 (no barrier — overlaps next ph0)
        if (t + 2 < nt) STAGE_B(t + 2);
        __builtin_amdgcn_s_setprio(1);
        #pragma unroll
        for (int mi = 0; mi < 4; ++mi)
            #pragma unroll
            for (int nj = 2; nj < 4; ++nj)
                acc[mi][nj] = __builtin_amdgcn_mfma_f32_16x16x32_bf16(
                    af1[mi], bq1[nj], acc[mi][nj], 0, 0, 0);
        __builtin_amdgcn_s_setprio(0);
    }

    // C/D layout: col = lane&15, row = (lane>>4)*4 + reg   [m89/m91]
    const int rq = lh * 4;
    bf16* Cbz = Cb;
    if (EPI == 3) Cbz += (size_t)bz * 2048 * N;
    #pragma unroll
    for (int mi = 0; mi < 4; ++mi) {
        #pragma unroll
        for (int rj = 0; rj < 4; ++rj) {
            int row = row0 + wm * 64 + mi * 16 + rq + rj;
            #pragma unroll
            for (int nj = 0; nj < 4; ++nj) {
                int col = col0 + wn * 64 + nj * 16 + rl;
                float c = acc[mi][nj][rj];
                size_t off = (size_t)row * N + col;
                if (EPI == 1) Cbz[off] = (bf16)gelu_exact(c + bias[col]);
                else          Cbz[off] = (bf16)c;
            }
        }
    }
}

// ---------------- gemm6: 64x128 tile, 4 waves, ping-pong (small GEMMs) -----
template<int EPI>
__global__ __launch_bounds__(256, 4) void gemm6_kernel(
    const bf16* __restrict__ A, const bf16* __restrict__ Wt,
    const float* __restrict__ bias,
    float* Cf, bf16* Cb, int N, int Kp, int ksplit)
{
    __shared__ __align__(16) char lds[2][12288];   // per buf: A 4KB | B 8KB

    const int tid  = threadIdx.x;
    const int w    = tid >> 6;
    const int lane = tid & 63;

    const int gx = gridDim.x, gy = gridDim.y;
    const int nwg = gx * gy * gridDim.z;
    const int chunk = nwg >> 3;
    int id = (blockIdx.z * gy + blockIdx.y) * gx + blockIdx.x;
    int sw = (id & 7) * chunk + (id >> 3);
    const int bx = sw % gx;
    const int t2 = sw / gx;
    const int by = t2 % gy;
    const int bz = t2 / gy;

    const int row0 = by * 64;
    const int col0 = bx * 128;
    const int wr = (w >> 1) * 32;
    const int wc = (w & 1) * 64;
    const int rl = lane & 15;
    const int kb16 = (lane >> 4) * 16;

    const size_t strideBy = (size_t)Kp * 2;
    const size_t kz = (size_t)bz * ksplit * 2;
    const char* Abase = (const char*)A  + (size_t)row0 * strideBy + kz;
    const char* Wbase = (const char*)Wt + (size_t)col0 * strideBy + kz;

    const size_t srcA0 = (size_t)(tid >> 2) * strideBy + (tid & 3) * 16;
    size_t srcB[2];
    #pragma unroll
    for (int i = 0; i < 2; ++i) {
        int o = (i * 256 + tid) * 16;
        srcB[i] = (size_t)(o >> 6) * strideBy + (o & 63);
    }

    f32x4 acc[2][4] = {};

    auto STAGE = [&](int buf, int kt) {
        const char* ab = Abase + (size_t)kt * 64;
        const char* wb = Wbase + (size_t)kt * 64;
        gload16(ab + srcA0, &lds[buf][0] + tid * 16);
        #pragma unroll
        for (int i = 0; i < 2; ++i)
            gload16(wb + srcB[i], &lds[buf][4096] + (i * 256 + tid) * 16);
    };

    const int niter = ksplit >> 5;      // BK = 32
    STAGE(0, 0);
    __syncthreads();
    for (int kt = 0; kt < niter; ++kt) {
        if (kt + 1 < niter)
            STAGE((kt + 1) & 1, kt + 1);
        const char* base = lds[kt & 1];
        bf16x8 af[2], bfr[4];
        #pragma unroll
        for (int mi = 0; mi < 2; ++mi)
            af[mi] = *(const bf16x8*)(base + ((wr + mi*16 + rl) << 6) + kb16);
        #pragma unroll
        for (int nj = 0; nj < 4; ++nj)
            bfr[nj] = *(const bf16x8*)(base + 4096 + ((wc + nj*16 + rl) << 6) + kb16);
        __builtin_amdgcn_s_setprio(1);
        #pragma unroll
        for (int mi = 0; mi < 2; ++mi)
            #pragma unroll
            for (int nj = 0; nj < 4; ++nj)
                acc[mi][nj] = __builtin_amdgcn_mfma_f32_16x16x32_bf16(
                    af[mi], bfr[nj], acc[mi][nj], 0, 0, 0);
        __builtin_amdgcn_s_setprio(0);
        __syncthreads();
    }

    const int rq = (lane >> 4) * 4;
    bf16* Cbz = Cb;
    if (EPI == 3) Cbz += (size_t)bz * 2048 * N;
    #pragma unroll
    for (int mi = 0; mi < 2; ++mi) {
        #pragma unroll
        for (int rj = 0; rj < 4; ++rj) {
            int row = row0 + wr + mi*16 + rq + rj;
            #pragma unroll
            for (int nj = 0; nj < 4; ++nj) {
                int col = col0 + wc + nj*16 + rl;
                float c = acc[mi][nj][rj];
                if (EPI != 3) c += bias[col];
                size_t off = (size_t)row * N + col;
                if (EPI == 0)      Cb[off]  = (bf16)c;
                else               Cbz[off] = (bf16)c;
            }
        }
    }
}

// ---------------- split-K reducer: out = R + bias + sum(parts) -------------
template<int P>
__global__ __launch_bounds__(256) void reduce_kernel(
    const bf16* __restrict__ parts, const float* __restrict__ bias,
    const float* R, float* out)
{
    int row = blockIdx.x;
    int c = threadIdx.x * 4;
    size_t off = (size_t)row * 1024 + c;
    float4 bv = *(const float4*)(bias + c);
    float4 o = *(const float4*)(R + off);
    o.x += bv.x; o.y += bv.y; o.z += bv.z; o.w += bv.w;
    #pragma unroll
    for (int p = 0; p < P; ++p) {
        bf16x4 v = *(const bf16x4*)(parts + (size_t)p * 2048 * 1024 + off);
        o.x += (float)v[0]; o.y += (float)v[1];
        o.z += (float)v[2]; o.w += (float)v[3];
    }
    *(float4*)(out + off) = o;
}

// ---------------- windowed attention, one wave per (b,h,t) token ----------
__global__ __launch_bounds__(256) void attn_kernel(
    const bf16* __restrict__ qkv, const float* __restrict__ rel_pos,
    bf16* __restrict__ outp)
{
    __shared__ float sbias[64*65];
    __shared__ float kmw[4][3][64];
    for (int i = threadIdx.x; i < 63*63; i += 256) {
        int d = i / 63, v = i - d*63;
        sbias[d*65 + v] = rel_pos[((d + 32) % 63) * 63 + v];
    }
    __syncthreads();
    const int wave = threadIdx.x >> 6;
    const int lane = threadIdx.x & 63;
    const int tk  = blockIdx.x * 4 + wave;
    const int row = tk >> 3;
    const int h   = tk & 7;
    const bf16* base = qkv + (size_t)row * 1536 + h * 63;
    float q_own = 0.f, k_own = 0.f, v_own = 0.f;
    if (lane < 63) {
        q_own = (float)base[lane];
        k_own = (float)base[504 + lane];
        v_own = (float)base[1008 + lane];
    }
    float m = -1e30f;
    for (int d = 0; d < 63; ++d) {
        float qd = __shfl(q_own, d);
        m = fmaxf(m, fmaf(qd, k_own, sbias[d*65 + lane]));
    }
    float Z = 0.f;
    for (int d = 0; d < 63; ++d) {
        float qd = __shfl(q_own, d);
        Z += __expf(fmaf(qd, k_own, sbias[d*65 + lane]) - m);
    }
    kmw[wave][0][lane] = k_own;
    kmw[wave][1][lane] = m;
    kmw[wave][2][lane] = v_own / Z;
    float acc = 0.f;
    for (int v = 0; v < 63; ++v) {
        float s = fmaf(q_own, kmw[wave][0][v], sbias[lane*65 + v]) - kmw[wave][1][v];
        acc += __expf(s) * kmw[wave][2][v];
    }
    if (lane < 63)
        outp[(size_t)row * 512 + h*63 + lane] = (bf16)acc;
    if (h == 7 && lane == 63) {
        #pragma unroll
        for (int j = 0; j < 8; ++j)
            outp[(size_t)row * 512 + 504 + j] = (bf16)0.f;
    }
}

extern "C" void kernel_launch(void* const* d_in, const int* in_sizes, int n_in,
                              void* d_out, int out_size, void* d_ws, size_t ws_size,
                              hipStream_t stream)
{
    const float* x       = (const float*)d_in[0];
    const float* ln1_w   = (const float*)d_in[1];
    const float* ln1_b   = (const float*)d_in[2];
    const float* qkv_w   = (const float*)d_in[3];
    const float* qkv_b   = (const float*)d_in[4];
    const float* rel_pos = (const float*)d_in[5];
    const float* proj_w  = (const float*)d_in[6];
    const float* proj_b  = (const float*)d_in[7];
    const float* ln2_w   = (const float*)d_in[8];
    const float* ln2_b   = (const float*)d_in[9];
    const float* fc_w    = (const float*)d_in[10];
    const float* fc_b    = (const float*)d_in[11];
    const float* cproj_w = (const float*)d_in[12];
    const float* cproj_b = (const float*)d_in[13];
    float* out = (float*)d_out;

    // ---- workspace layout (bytes), total ~50 MB ----
    char* p = (char*)d_ws;
    float* xr      = (float*)p;            p += (size_t)2048*1024*4;   // 8 MB  [0,8M)
    bf16*  h_bf    = (bf16*)p;             p += (size_t)2048*1024*2;   // 4 MB  [8,12M)
    bf16*  wqkv    = (bf16*)p;             p += (size_t)1536*1024*2;   // 3 MB
    bf16*  wproj   = (bf16*)p;             p += (size_t)1024*512*2;    // 1 MB
    bf16*  wfc     = (bf16*)p;             p += (size_t)4096*1024*2;   // 8 MB
    bf16*  wcproj  = (bf16*)p;             p += (size_t)1024*4096*2;   // 8 MB
    float* qkvb_p  = (float*)p;            p += 8192;                  // 6 KB pad
    bf16*  attn_bf = (bf16*)p;             p += (size_t)2048*512*2;    // 2 MB
    bf16*  qkvb    = (bf16*)p;                                         // 6 MB
    bf16*  fc_act  = (bf16*)p;             // 16 MB, overlaps qkvb (dead after attn)
    bf16*  proj_part = qkvb;               // 2 x 4 MB (dead before fc writes fc_act)
    bf16*  cp_part = (bf16*)d_ws;          // 4 x 4 MB over xr/h_bf/wqkv/wproj (dead)

    conv_all_kernel<<<5121, 256, 0, stream>>>(qkv_w, proj_w, fc_w, cproj_w, qkv_b,
                                              wqkv, wproj, wfc, wcproj, qkvb_p);
    rotary_ln_kernel<<<2048, 256, 0, stream>>>(x, ln1_w, ln1_b, xr, h_bf);
    // qkv: M=2048 N=1536 K=1024 -> 12x32 = 384 WGs
    gemm6_kernel<0><<<dim3(12,32,1), 256, 0, stream>>>(h_bf, wqkv, qkvb_p,
                                                       nullptr, qkvb, 1536, 1024, 1024);
    attn_kernel<<<4096, 256, 0, stream>>>(qkvb, rel_pos, attn_bf);
    // proj: M=2048 N=1024 K=512, split-K2 -> 8x32x2 = 512 WGs
    gemm6_kernel<3><<<dim3(8,32,2), 256, 0, stream>>>(attn_bf, wproj, nullptr,
                                                      nullptr, proj_part, 1024, 512, 256);
    reduce_kernel<2><<<2048, 256, 0, stream>>>(proj_part, proj_b, xr, out);
    ln_bf16_kernel<<<2048, 256, 0, stream>>>(out, ln2_w, ln2_b, h_bf);
    // fc: M=2048 N=4096 K=1024 -> gemm8p 16x16 = 256 WGs
    gemm8p_kernel<1><<<dim3(16,16,1), 512, 0, stream>>>(h_bf, wfc, fc_b,
                                                        fc_act, 4096, 1024, 1024);
    // cproj: M=2048 N=1024 K=4096, split-K4 -> gemm8p 4x16x4 = 256 WGs
    gemm8p_kernel<3><<<dim3(4,16,4), 512, 0, stream>>>(fc_act, wcproj, nullptr,
                                                       cp_part, 1024, 4096, 1024);
    reduce_kernel<4><<<2048, 256, 0, stream>>>(cp_part, cproj_b, out, out);
}